// Round 5
// baseline (11.155 us; speedup 1.0000x reference)
//
#include <hip/hip_runtime.h>
#include <math.h>

#define TPB 256
#define KQ 4
#define OPT 16   // outputs per thread

__device__ __forceinline__ void elemCGH(float v, float& c, float& g, float& h) {
    float t2 = v * v;
    c = __builtin_amdgcn_rsqf(1.0f + t2);            // cos(atan(x))
    float d = __builtin_amdgcn_rsqf(1.0f + t2 * t2); // cos(atan(x^2))
    g = v * c * d;                                   // sin(atan(x))cos(atan(x^2))
    h = t2 * g;                                      // sin(atan(x))sin(atan(x^2))
}

__device__ __forceinline__ float qout1(const float* __restrict__ row, int p,
                                       float W0, float W1, float W2) {
    float c0, g0, h0, c1, g1, h1, c2, g2, h2, c3, g3, h3;
    elemCGH(row[p],     c0, g0, h0);
    elemCGH(row[p + 1], c1, g1, h1);
    elemCGH(row[p + 2], c2, g2, h2);
    elemCGH(row[p + 3], c3, g3, h3);
    float cc = c2 * c3;
    return W0 * (c1 * cc) + W1 * (g0 * g1) + W2 * (g0 * h1 * cc);
}

__global__ __launch_bounds__(TPB) void qconv4_kernel(
    const float* __restrict__ x, const float* __restrict__ w,
    float* __restrict__ out, int N, int L)
{
    const int b = blockIdx.y;
    const float* __restrict__ row  = x   + (size_t)b * N;
    float* __restrict__       orow = out + (size_t)b * L;

    // Row b's outputs start at flat index b*L; L % 4 == 1 -> start ≡ b (mod 4).
    // Shift by a so each thread's 16 outputs form four 16B-aligned float4 stores.
    const int a = (4 - (b & 3)) & 3;
    const int ngroups = (L - a) >> 4;   // groups of 16

    // <Z> = cos(th)*c1c2c3 - sin(th)cos(ph)*g0g1 + sin(th)sin(ph)*g0h1c2c3
    const float ph = w[0], th = w[1];
    float sth, cth, sph, cph;
    __sincosf(th, &sth, &cth);
    __sincosf(ph, &sph, &cph);
    const float W0 = cth, W1 = -sth * cph, W2 = sth * sph;

    const int j = blockIdx.x * TPB + threadIdx.x;

    if (j < ngroups) {
        const int l = a + OPT * j;  // needs x[l .. l+18]; max <= L+2 = 8191 < N
        float c[OPT + 3], g[OPT + 3], h[OPT + 3];
        #pragma unroll
        for (int e = 0; e < OPT + 3; ++e)
            elemCGH(row[l + e], c[e], g[e], h[e]);

        float r[OPT];
        #pragma unroll
        for (int e = 0; e < OPT; ++e) {
            float cc = c[e + 2] * c[e + 3];
            r[e] = W0 * (c[e + 1] * cc) + W1 * (g[e] * g[e + 1]) + W2 * (g[e] * h[e + 1] * cc);
        }
        #pragma unroll
        for (int q = 0; q < OPT / 4; ++q)
            *reinterpret_cast<float4*>(orow + l + 4 * q) =
                make_float4(r[4*q], r[4*q + 1], r[4*q + 2], r[4*q + 3]);
    }
    if (j == 0) {
        // prefix [0, a) and tail [a + 16*ngroups, L) — ≤ ~19 scalar outputs
        for (int p = 0; p < a; ++p)
            orow[p] = qout1(row, p, W0, W1, W2);
        for (int p = a + OPT * ngroups; p < L; ++p)
            orow[p] = qout1(row, p, W0, W1, W2);
    }
}

extern "C" void kernel_launch(void* const* d_in, const int* in_sizes, int n_in,
                              void* d_out, int out_size, void* d_ws, size_t ws_size,
                              hipStream_t stream) {
    const float* x = (const float*)d_in[0];
    const float* w = (const float*)d_in[1];
    float* out = (float*)d_out;

    const int B = 128;
    const int N = in_sizes[0] / B;   // 8192
    const int L = N - KQ + 1;        // 8189

    // per row: ngroups <= 511 threads (+ thread 0 cleanup) -> 2 blocks of 256
    dim3 grid(2, B);
    qconv4_kernel<<<grid, TPB, 0, stream>>>(x, w, out, N, L);
}